// Round 1
// baseline (2277.154 us; speedup 1.0000x reference)
//
#include <hip/hip_runtime.h>
#include <hip/hip_bf16.h>
#include <math.h>

#define N_PIX 65536
#define W_IMG 256
#define H_IMG 256
#define BATCH 2

typedef unsigned short u16;

__device__ __forceinline__ float bf2f(u16 u) {
  union { unsigned u; float f; } v; v.u = ((unsigned)u) << 16; return v.f;
}
__device__ __forceinline__ u16 f2bf(float f) {
  union { float f; unsigned u; } v; v.f = f;
  unsigned r = v.u + 0x7FFFu + ((v.u >> 16) & 1u);
  return (u16)(r >> 16);
}

// K1: LayerNorm over channels + conv1x1 w_qkv (64 -> 192), bf16 out
__global__ __launch_bounds__(256) void k_ln_qkv(
    const float* __restrict__ x, const float* __restrict__ n1w,
    const float* __restrict__ n1b, const float* __restrict__ wqkv,
    u16* __restrict__ qkvp)
{
  const int n = blockIdx.x * 256 + threadIdx.x;
  const int b = blockIdx.y;
  const float* xb = x + ((size_t)b * 64) * N_PIX + n;
  float y[64];
  float mu = 0.f;
#pragma unroll
  for (int c = 0; c < 64; ++c) { y[c] = xb[(size_t)c * N_PIX]; mu += y[c]; }
  mu *= (1.f / 64.f);
  float var = 0.f;
#pragma unroll
  for (int c = 0; c < 64; ++c) { float d = y[c] - mu; var = fmaf(d, d, var); }
  const float rstd = rsqrtf(var * (1.f / 64.f) + 1e-5f);
#pragma unroll
  for (int c = 0; c < 64; ++c) y[c] = (y[c] - mu) * rstd * n1w[c] + n1b[c];

  u16* ob = qkvp + ((size_t)b * 192) * N_PIX + n;
  for (int oc = 0; oc < 3; ++oc) {
    const float* wr = wqkv + oc * 64 * 64;
    float acc[64];
#pragma unroll
    for (int o = 0; o < 64; ++o) acc[o] = 0.f;
#pragma unroll
    for (int c = 0; c < 64; ++c) {
      const float yv = y[c];
#pragma unroll
      for (int o = 0; o < 64; ++o) acc[o] = fmaf(wr[o * 64 + c], yv, acc[o]);
    }
#pragma unroll
    for (int o = 0; o < 64; ++o) ob[(size_t)(oc * 64 + o) * N_PIX] = f2bf(acc[o]);
  }
}

// Depthwise 3x3 SAME, bf16 in/out; weight row = wofs + (plane % planes_per_b)
__global__ __launch_bounds__(256) void k_dw3(
    const u16* __restrict__ in, u16* __restrict__ out,
    const float* __restrict__ wdw, int planes_per_b, int wofs)
{
  const int y = blockIdx.x;
  const int plane = blockIdx.y;
  const int c = plane % planes_per_b;
  const int xc = threadIdx.x;
  const u16* pin = in + (size_t)plane * N_PIX;
  const float* wc = wdw + (size_t)(wofs + c) * 9;
  float acc = 0.f;
#pragma unroll
  for (int ky = 0; ky < 3; ++ky) {
    const int yy = y + ky - 1;
    if (yy < 0 || yy >= H_IMG) continue;
    const u16* row = pin + yy * W_IMG;
#pragma unroll
    for (int kx = 0; kx < 3; ++kx) {
      const int xx = xc + kx - 1;
      if (xx < 0 || xx >= W_IMG) continue;
      acc = fmaf(wc[ky * 3 + kx], bf2f(row[xx]), acc);
    }
  }
  out[(size_t)plane * N_PIX + y * W_IMG + xc] = f2bf(acc);
}

// K3a: per-(b,head,chunk) partial Gram (16x16) + partial q/k squared norms
#define GC 512
__global__ __launch_bounds__(256) void k_gram(
    const u16* __restrict__ qkv, float* __restrict__ part)
{
  __shared__ u16 lq[16][GC + 8];
  __shared__ u16 lk[16][GC + 8];
  const int chunk = blockIdx.x;  // 0..127
  const int h = blockIdx.y;      // 0..3
  const int b = blockIdx.z;      // 0..1
  const int t = threadIdx.x;
  const size_t base_q = ((size_t)(b * 192 + h * 16)) * N_PIX + chunk * GC;
  const size_t base_k = ((size_t)(b * 192 + 64 + h * 16)) * N_PIX + chunk * GC;
#pragma unroll
  for (int r = 0; r < 16; ++r) {
    lq[r][t]       = qkv[base_q + (size_t)r * N_PIX + t];
    lq[r][t + 256] = qkv[base_q + (size_t)r * N_PIX + t + 256];
    lk[r][t]       = qkv[base_k + (size_t)r * N_PIX + t];
    lk[r][t + 256] = qkv[base_k + (size_t)r * N_PIX + t + 256];
  }
  __syncthreads();
  const int d = t >> 4, e = t & 15;
  float acc = 0.f;
  for (int i = 0; i < GC; ++i)
    acc = fmaf(bf2f(lq[d][i]), bf2f(lk[e][i]), acc);
  float* pp = part + (((size_t)(b * 4 + h) * 128 + chunk) * 288);
  pp[t] = acc;
  if (t < 32) {
    const int r = t & 15;
    const u16* row = (t < 16) ? lq[r] : lk[r];
    float s = 0.f;
    for (int i = 0; i < GC; ++i) { float v = bf2f(row[i]); s = fmaf(v, v, s); }
    pp[256 + t] = s;
  }
}

// K3b: reduce partials over 128 chunks
__global__ __launch_bounds__(320) void k_gram_red(
    const float* __restrict__ part, float* __restrict__ G,
    float* __restrict__ Sq, float* __restrict__ Sk)
{
  const int bh = blockIdx.x;  // b*4+h
  const int t = threadIdx.x;
  if (t >= 288) return;
  const float* p = part + (size_t)bh * 128 * 288 + t;
  float s = 0.f;
  for (int ch = 0; ch < 128; ++ch) s += p[(size_t)ch * 288];
  const int b = bh >> 2, h = bh & 3;
  if (t < 256) G[bh * 256 + t] = s;
  else if (t < 272) Sq[b * 64 + h * 16 + (t - 256)] = s;
  else Sk[b * 64 + h * 16 + (t - 272)] = s;
}

// K4: softmax(attn) then fold conv matrices:
//   M1 = w_po  * blockdiag(attn);  P = w_kv[64:128] * M1;  M2 = w_pof * blockdiag(attn)
__global__ __launch_bounds__(256) void k_attn(
    const float* __restrict__ G, const float* __restrict__ Sq,
    const float* __restrict__ Sk, const float* __restrict__ temp,
    const float* __restrict__ wpo, const float* __restrict__ wkv,
    const float* __restrict__ wpof, float* __restrict__ P,
    float* __restrict__ M2)
{
  __shared__ float attn[BATCH][4][16][16];
  __shared__ float M1[BATCH][64][64];
  __shared__ float rq[128], rk[128];
  const int t = threadIdx.x;
  if (t < 128) {
    rq[t] = 1.f / fmaxf(sqrtf(Sq[t]), 1e-12f);
    rk[t] = 1.f / fmaxf(sqrtf(Sk[t]), 1e-12f);
  }
  __syncthreads();
  if (t < 128) {
    const int b = t >> 6, h = (t >> 4) & 3, d = t & 15;
    const float tm = temp[h];
    const float* g = G + ((b * 4 + h) * 16 + d) * 16;
    const float rqd = rq[b * 64 + h * 16 + d];
    float L[16], mx = -1e30f;
#pragma unroll
    for (int e = 0; e < 16; ++e) {
      L[e] = g[e] * rqd * rk[b * 64 + h * 16 + e] * tm;
      mx = fmaxf(mx, L[e]);
    }
    float s = 0.f;
#pragma unroll
    for (int e = 0; e < 16; ++e) { L[e] = expf(L[e] - mx); s += L[e]; }
    const float inv = 1.f / s;
#pragma unroll
    for (int e = 0; e < 16; ++e) attn[b][h][d][e] = L[e] * inv;
  }
  __syncthreads();
  for (int s0 = 0; s0 < 32; ++s0) {
    const int idx = t * 32 + s0;
    const int b = idx >> 12, o = (idx >> 6) & 63, c = idx & 63;
    const int h = c >> 4, e = c & 15;
    float a = 0.f;
#pragma unroll
    for (int d = 0; d < 16; ++d) a = fmaf(wpo[o * 64 + h * 16 + d], attn[b][h][d][e], a);
    M1[b][o][c] = a;
  }
  __syncthreads();
  for (int s0 = 0; s0 < 32; ++s0) {
    const int idx = t * 32 + s0;
    const int b = idx >> 12, o = (idx >> 6) & 63, c = idx & 63;
    const int h = c >> 4, e = c & 15;
    float a = 0.f;
    for (int j = 0; j < 64; ++j) a = fmaf(wkv[(64 + o) * 64 + j], M1[b][j][c], a);
    P[(b * 64 + o) * 64 + c] = a;
    float a2 = 0.f;
#pragma unroll
    for (int d = 0; d < 16; ++d) a2 = fmaf(wpof[o * 64 + h * 16 + d], attn[b][h][d][e], a2);
    M2[(b * 64 + o) * 64 + c] = a2;
  }
}

// K5: vf_pre = P[b] * v  (per-pixel 64x64)
__global__ __launch_bounds__(256) void k_pv(
    const u16* __restrict__ qkv, const float* __restrict__ P,
    u16* __restrict__ vfp)
{
  const int n = blockIdx.x * 256 + threadIdx.x;
  const int b = blockIdx.y;
  const u16* vb = qkv + ((size_t)(b * 192 + 128)) * N_PIX + n;
  float vin[64];
#pragma unroll
  for (int c = 0; c < 64; ++c) vin[c] = bf2f(vb[(size_t)c * N_PIX]);
  const float* Pb = P + b * 4096;
  float acc[64];
#pragma unroll
  for (int o = 0; o < 64; ++o) acc[o] = 0.f;
#pragma unroll
  for (int c = 0; c < 64; ++c) {
    const float v = vin[c];
#pragma unroll
    for (int o = 0; o < 64; ++o) acc[o] = fmaf(Pb[o * 64 + c], v, acc[o]);
  }
  u16* ob = vfp + ((size_t)b * 64) * N_PIX + n;
#pragma unroll
  for (int o = 0; o < 64; ++o) ob[(size_t)o * N_PIX] = f2bf(acc[o]);
}

// K7: x2 = x + M2*vf (residual), write x2 f32; LN2; conv1x1 w_in (64->340) bf16
__global__ __launch_bounds__(256) void k_x2_ln_win(
    const float* __restrict__ x, const u16* __restrict__ vf,
    const float* __restrict__ M2, const float* __restrict__ n2w,
    const float* __restrict__ n2b, const float* __restrict__ win,
    float* __restrict__ x2, u16* __restrict__ hpre)
{
  const int n = blockIdx.x * 256 + threadIdx.x;
  const int b = blockIdx.y;
  const u16* vb = vf + ((size_t)b * 64) * N_PIX + n;
  float vin[64];
#pragma unroll
  for (int c = 0; c < 64; ++c) vin[c] = bf2f(vb[(size_t)c * N_PIX]);
  const float* Mb = M2 + b * 4096;
  float acc[64];
#pragma unroll
  for (int o = 0; o < 64; ++o) acc[o] = 0.f;
#pragma unroll
  for (int c = 0; c < 64; ++c) {
    const float v = vin[c];
#pragma unroll
    for (int o = 0; o < 64; ++o) acc[o] = fmaf(Mb[o * 64 + c], v, acc[o]);
  }
  const float* xb = x + ((size_t)b * 64) * N_PIX + n;
  float* x2b = x2 + ((size_t)b * 64) * N_PIX + n;
  float mu = 0.f;
#pragma unroll
  for (int o = 0; o < 64; ++o) {
    const float v = xb[(size_t)o * N_PIX] + acc[o];
    x2b[(size_t)o * N_PIX] = v;
    acc[o] = v;
    mu += v;
  }
  mu *= (1.f / 64.f);
  float var = 0.f;
#pragma unroll
  for (int o = 0; o < 64; ++o) { const float d = acc[o] - mu; var = fmaf(d, d, var); }
  const float rstd = rsqrtf(var * (1.f / 64.f) + 1e-5f);
#pragma unroll
  for (int o = 0; o < 64; ++o) acc[o] = (acc[o] - mu) * rstd * n2w[o] + n2b[o];

  u16* hb = hpre + ((size_t)b * 340) * N_PIX + n;
  for (int oc = 0; oc < 5; ++oc) {
    const float* wr = win + (oc * 68) * 64;
    float a2[68];
#pragma unroll
    for (int o = 0; o < 68; ++o) a2[o] = 0.f;
#pragma unroll
    for (int c = 0; c < 64; ++c) {
      const float yv = acc[c];
#pragma unroll
      for (int o = 0; o < 68; ++o) a2[o] = fmaf(wr[o * 64 + c], yv, a2[o]);
    }
#pragma unroll
    for (int o = 0; o < 68; ++o) hb[(size_t)(oc * 68 + o) * N_PIX] = f2bf(a2[o]);
  }
}

// K9: g = gelu(x1)*x2gate; out = x2 + w_out * g
__global__ __launch_bounds__(256) void k_gdfn_out(
    const u16* __restrict__ hpost, const float* __restrict__ x2,
    const float* __restrict__ wout, float* __restrict__ out)
{
  const int n = blockIdx.x * 256 + threadIdx.x;
  const int b = blockIdx.y;
  const u16* hb = hpost + ((size_t)b * 340) * N_PIX + n;
  float acc[64];
#pragma unroll
  for (int o = 0; o < 64; ++o) acc[o] = 0.f;
  for (int c = 0; c < 170; ++c) {
    const float a  = bf2f(hb[(size_t)c * N_PIX]);
    const float v2 = bf2f(hb[(size_t)(170 + c) * N_PIX]);
    const float g = 0.5f * a * (1.f + erff(a * 0.70710678118f)) * v2;
#pragma unroll
    for (int o = 0; o < 64; ++o) acc[o] = fmaf(wout[o * 170 + c], g, acc[o]);
  }
  const float* x2b = x2 + ((size_t)b * 64) * N_PIX + n;
  float* ob = out + ((size_t)b * 64) * N_PIX + n;
#pragma unroll
  for (int o = 0; o < 64; ++o) ob[(size_t)o * N_PIX] = x2b[(size_t)o * N_PIX] + acc[o];
}

extern "C" void kernel_launch(void* const* d_in, const int* in_sizes, int n_in,
                              void* d_out, int out_size, void* d_ws, size_t ws_size,
                              hipStream_t stream)
{
  const float* x     = (const float*)d_in[0];
  const float* n1w   = (const float*)d_in[1];
  const float* n1b   = (const float*)d_in[2];
  const float* temp  = (const float*)d_in[3];
  const float* wqkv  = (const float*)d_in[4];
  const float* wqkvd = (const float*)d_in[5];
  const float* wpo   = (const float*)d_in[6];
  const float* wkv   = (const float*)d_in[7];
  const float* wkvd  = (const float*)d_in[8];
  const float* wpof  = (const float*)d_in[9];
  const float* n2w   = (const float*)d_in[10];
  const float* n2b   = (const float*)d_in[11];
  const float* win   = (const float*)d_in[12];
  const float* wdw   = (const float*)d_in[13];
  const float* wout  = (const float*)d_in[14];
  float* out = (float*)d_out;

  char* ws = (char*)d_ws;
  const size_t R1_SZ = (size_t)BATCH * 340 * N_PIX * 2;  // 89,128,960 B
  const size_t R2_SZ = R1_SZ;
  // R1: qkv_pre (first 50.3MB), later hpre (full)
  u16* qkvp  = (u16*)(ws);
  u16* hpre  = (u16*)(ws);
  // R2: qkv (50.3MB) | vfpre (16.8MB) | vf (16.8MB); later hpost (full)
  u16* qkv   = (u16*)(ws + R1_SZ);
  u16* hpost = (u16*)(ws + R1_SZ);
  u16* vfp   = (u16*)(ws + R1_SZ + (size_t)BATCH * 192 * N_PIX * 2);
  u16* vf    = (u16*)(ws + R1_SZ + (size_t)BATCH * 192 * N_PIX * 2 + (size_t)BATCH * 64 * N_PIX * 2);
  float* x2  = (float*)(ws + R1_SZ + R2_SZ);
  char* sm   = ws + R1_SZ + R2_SZ + (size_t)BATCH * 64 * N_PIX * 4;
  float* part = (float*)sm;                                  // 1,179,648 B
  float* G    = (float*)(sm + 1179648);                      // 8 KB
  float* Sq   = (float*)(sm + 1179648 + 8192);               // 512 B
  float* Sk   = (float*)(sm + 1179648 + 8192 + 512);         // 512 B
  float* P    = (float*)(sm + 1179648 + 8192 + 1024);        // 32 KB
  float* M2   = (float*)(sm + 1179648 + 8192 + 1024 + 32768);// 32 KB

  k_ln_qkv<<<dim3(N_PIX / 256, BATCH), 256, 0, stream>>>(x, n1w, n1b, wqkv, qkvp);
  k_dw3<<<dim3(H_IMG, BATCH * 192), 256, 0, stream>>>(qkvp, qkv, wqkvd, 192, 0);
  k_gram<<<dim3(128, 4, BATCH), 256, 0, stream>>>(qkv, part);
  k_gram_red<<<dim3(BATCH * 4), 320, 0, stream>>>(part, G, Sq, Sk);
  k_attn<<<dim3(1), 256, 0, stream>>>(G, Sq, Sk, temp, wpo, wkv, wpof, P, M2);
  k_pv<<<dim3(N_PIX / 256, BATCH), 256, 0, stream>>>(qkv, P, vfp);
  k_dw3<<<dim3(H_IMG, BATCH * 64), 256, 0, stream>>>(vfp, vf, wkvd, 64, 64);
  k_x2_ln_win<<<dim3(N_PIX / 256, BATCH), 256, 0, stream>>>(x, vf, M2, n2w, n2b, win, x2, hpre);
  k_dw3<<<dim3(H_IMG, BATCH * 340), 256, 0, stream>>>(hpre, hpost, wdw, 340, 0);
  k_gdfn_out<<<dim3(N_PIX / 256, BATCH), 256, 0, stream>>>(hpost, x2, wout, out);
}

// Round 2
// 582.418 us; speedup vs baseline: 3.9098x; 3.9098x over previous
//
#include <hip/hip_runtime.h>
#include <hip/hip_bf16.h>
#include <math.h>

#define NPB 65536   // pixels per batch (256*256)
#define BATCH 2

typedef unsigned short u16;
typedef __attribute__((ext_vector_type(8))) short short8;
typedef __attribute__((ext_vector_type(4))) float f32x4;

__device__ __forceinline__ float bf2f(u16 u) {
  union { unsigned u; float f; } v; v.u = ((unsigned)u) << 16; return v.f;
}
__device__ __forceinline__ u16 f2bf(float f) {
  union { float f; unsigned u; } v; v.f = f;
  unsigned r = v.u + 0x7FFFu + ((v.u >> 16) & 1u);
  return (u16)(r >> 16);
}
__device__ __forceinline__ unsigned pk2(float a, float b) {
  return (unsigned)f2bf(a) | ((unsigned)f2bf(b) << 16);
}
__device__ __forceinline__ f32x4 mm(short8 a, short8 b, f32x4 c) {
  return __builtin_amdgcn_mfma_f32_16x16x32_bf16(a, b, c, 0, 0, 0);
}
// Build an A-fragment from an f32 weight matrix. row<0 or k>=kval -> 0.
__device__ __forceinline__ short8 afrag(const float* W, int ld, int row, int k0, int kval) {
  short8 r;
#pragma unroll
  for (int j = 0; j < 8; ++j) {
    float v = 0.f;
    if (row >= 0 && (k0 + j) < kval) v = W[(size_t)row * ld + k0 + j];
    r[j] = (short)f2bf(v);
  }
  return r;
}
__device__ __forceinline__ void st4(u16* p, f32x4 c) {
  uint2 v; v.x = pk2(c[0], c[1]); v.y = pk2(c[2], c[3]);
  *reinterpret_cast<uint2*>(p) = v;
}

// ---------------- K1: LN1, channel-major f32 -> pixel-major bf16 [n][64]
__global__ __launch_bounds__(256, 4) void k_ln1(
    const float* __restrict__ x, const float* __restrict__ n1w,
    const float* __restrict__ n1b, u16* __restrict__ Y1)
{
  const int n = blockIdx.x * 256 + threadIdx.x;
  const int b = blockIdx.y;
  const float* xb = x + ((size_t)b * 64) * NPB + n;
  float y[64];
  float mu = 0.f;
#pragma unroll
  for (int c = 0; c < 64; ++c) { y[c] = xb[(size_t)c * NPB]; mu += y[c]; }
  mu *= (1.f / 64.f);
  float var = 0.f;
#pragma unroll
  for (int c = 0; c < 64; ++c) { float d = y[c] - mu; var = fmaf(d, d, var); }
  const float rstd = rsqrtf(var * (1.f / 64.f) + 1e-5f);
#pragma unroll
  for (int c = 0; c < 64; ++c) y[c] = (y[c] - mu) * rstd * n1w[c] + n1b[c];
  u16* dst = Y1 + ((size_t)(b * NPB) + n) * 64;
#pragma unroll
  for (int g = 0; g < 8; ++g) {
    uint4 v;
    v.x = pk2(y[g*8+0], y[g*8+1]); v.y = pk2(y[g*8+2], y[g*8+3]);
    v.z = pk2(y[g*8+4], y[g*8+5]); v.w = pk2(y[g*8+6], y[g*8+7]);
    *reinterpret_cast<uint4*>(dst + g * 8) = v;
  }
}

// ---------------- G1: QKVp[n][192] = Wqkv(192x64) * Y1
__global__ __launch_bounds__(256, 2) void g_qkvp(
    const u16* __restrict__ Y1, const float* __restrict__ wq,
    u16* __restrict__ qkvp)
{
  const int l = threadIdx.x & 63, fr = l & 15, fq = l >> 4;
  const int wv = blockIdx.x * 4 + (threadIdx.x >> 6);
  const int nw = gridDim.x * 4;
  short8 A[12][2];
#pragma unroll
  for (int t = 0; t < 12; ++t)
#pragma unroll
    for (int kh = 0; kh < 2; ++kh)
      A[t][kh] = afrag(wq, 64, t * 16 + fr, kh * 32 + fq * 8, 64);
  for (int tile = wv; tile < 8192; tile += nw) {
    const size_t n0 = (size_t)tile * 16;
    const u16* yb = Y1 + (n0 + fr) * 64 + fq * 8;
    const short8 b0 = *reinterpret_cast<const short8*>(yb);
    const short8 b1 = *reinterpret_cast<const short8*>(yb + 32);
    f32x4 c[12];
#pragma unroll
    for (int t = 0; t < 12; ++t) c[t] = f32x4{0.f, 0.f, 0.f, 0.f};
#pragma unroll
    for (int t = 0; t < 12; ++t) c[t] = mm(A[t][0], b0, c[t]);
#pragma unroll
    for (int t = 0; t < 12; ++t) c[t] = mm(A[t][1], b1, c[t]);
    u16* ob = qkvp + (n0 + fr) * 192 + fq * 4;
#pragma unroll
    for (int t = 0; t < 12; ++t) st4(ob + t * 16, c[t]);
  }
}

// ---------------- depthwise 3x3 SAME on pixel-major [n][C], bf16
template<int C, int WOFS>
__global__ __launch_bounds__(256, 2) void k_dw3p(
    const u16* __restrict__ in, u16* __restrict__ out,
    const float* __restrict__ wdw)
{
  constexpr int NCG = C / 8;
  const int gid = blockIdx.x * 256 + threadIdx.x;
  const int cg = gid % NCG;
  const int rest = gid / NCG;
  const int strip = rest & 16383;
  const int b = rest >> 14;
  const int x0 = strip & 255;
  const int y0 = (strip >> 8) * 4;
  float w[9][8];
  const float* wb = wdw + (size_t)(WOFS + cg * 8) * 9;
#pragma unroll
  for (int i = 0; i < 8; ++i)
#pragma unroll
    for (int k = 0; k < 9; ++k) w[k][i] = wb[i * 9 + k];
  const u16* pin = in + (size_t)b * NPB * C;
  u16* pout = out + (size_t)b * NPB * C;
#pragma unroll
  for (int oy = 0; oy < 4; ++oy) {
    const int y = y0 + oy;
    float acc[8];
#pragma unroll
    for (int i = 0; i < 8; ++i) acc[i] = 0.f;
#pragma unroll
    for (int ky = 0; ky < 3; ++ky) {
      const int yy = y + ky - 1;
      if ((unsigned)yy >= 256u) continue;
#pragma unroll
      for (int kx = 0; kx < 3; ++kx) {
        const int xx = x0 + kx - 1;
        if ((unsigned)xx >= 256u) continue;
        const short8 v = *reinterpret_cast<const short8*>(
            pin + ((size_t)(yy * 256 + xx)) * C + cg * 8);
#pragma unroll
        for (int i = 0; i < 8; ++i)
          acc[i] = fmaf(w[ky * 3 + kx][i], bf2f((u16)v[i]), acc[i]);
      }
    }
    uint4 o;
    o.x = pk2(acc[0], acc[1]); o.y = pk2(acc[2], acc[3]);
    o.z = pk2(acc[4], acc[5]); o.w = pk2(acc[6], acc[7]);
    *reinterpret_cast<uint4*>(pout + ((size_t)(y * 256 + x0)) * C + cg * 8) = o;
  }
}

// ---------------- gram/norm partials via MFMA (Q^T K, Q^T Q, K^T K diag)
__global__ __launch_bounds__(256, 2) void k_gram_p(
    const u16* __restrict__ qkv, float* __restrict__ part)
{
  __shared__ __align__(16) u16 lds[32][520];
  const int chunk = blockIdx.x, h = blockIdx.y, b = blockIdx.z;
  const int t = threadIdx.x;
#pragma unroll
  for (int i = 0; i < 2; ++i) {
    const int p = t + i * 256;
    const u16* src = qkv + ((size_t)(b * NPB) + chunk * 512 + p) * 192 + h * 16;
    const short8 q0 = *reinterpret_cast<const short8*>(src);
    const short8 q1 = *reinterpret_cast<const short8*>(src + 8);
    const short8 k0 = *reinterpret_cast<const short8*>(src + 64);
    const short8 k1 = *reinterpret_cast<const short8*>(src + 72);
#pragma unroll
    for (int j = 0; j < 8; ++j) {
      lds[j][p] = (u16)q0[j];  lds[8 + j][p] = (u16)q1[j];
      lds[16 + j][p] = (u16)k0[j]; lds[24 + j][p] = (u16)k1[j];
    }
  }
  __syncthreads();
  const int w = t >> 6, l = t & 63, fr = l & 15, fq = l >> 4;
  if (w >= 3) return;
  float* pp = part + ((size_t)((b * 4 + h) * 128) + chunk) * 288;
  const int rowA = (w == 2) ? 16 + fr : fr;
  const int rowB = (w == 0) ? 16 + fr : rowA;
  f32x4 acc = {0.f, 0.f, 0.f, 0.f};
#pragma unroll
  for (int kt = 0; kt < 16; ++kt) {
    const short8 a  = *reinterpret_cast<const short8*>(&lds[rowA][kt * 32 + fq * 8]);
    const short8 bb = *reinterpret_cast<const short8*>(&lds[rowB][kt * 32 + fq * 8]);
    acc = mm(a, bb, acc);
  }
  if (w == 0) {
#pragma unroll
    for (int r = 0; r < 4; ++r) pp[(fq * 4 + r) * 16 + fr] = acc[r];
  } else if ((fr >> 2) == fq) {
    pp[(w == 1 ? 256 : 272) + fr] = acc[fr & 3];
  }
}

// ---------------- reduce partials over 128 chunks
__global__ __launch_bounds__(320) void k_gram_red(
    const float* __restrict__ part, float* __restrict__ G,
    float* __restrict__ Sq, float* __restrict__ Sk)
{
  const int bh = blockIdx.x;
  const int t = threadIdx.x;
  if (t >= 288) return;
  const float* p = part + (size_t)bh * 128 * 288 + t;
  float s = 0.f;
  for (int ch = 0; ch < 128; ++ch) s += p[(size_t)ch * 288];
  const int b = bh >> 2, h = bh & 3;
  if (t < 256) G[bh * 256 + t] = s;
  else if (t < 272) Sq[b * 64 + h * 16 + (t - 256)] = s;
  else Sk[b * 64 + h * 16 + (t - 272)] = s;
}

// ---------------- softmax + fold conv matrices (tiny, 1 block)
__global__ __launch_bounds__(256) void k_attn(
    const float* __restrict__ G, const float* __restrict__ Sq,
    const float* __restrict__ Sk, const float* __restrict__ temp,
    const float* __restrict__ wpo, const float* __restrict__ wkv,
    const float* __restrict__ wpof, float* __restrict__ P,
    float* __restrict__ M2)
{
  __shared__ float attn[BATCH][4][16][16];
  __shared__ float M1[BATCH][64][64];
  __shared__ float rq[128], rk[128];
  const int t = threadIdx.x;
  if (t < 128) {
    rq[t] = 1.f / fmaxf(sqrtf(Sq[t]), 1e-12f);
    rk[t] = 1.f / fmaxf(sqrtf(Sk[t]), 1e-12f);
  }
  __syncthreads();
  if (t < 128) {
    const int b = t >> 6, h = (t >> 4) & 3, d = t & 15;
    const float tm = temp[h];
    const float* g = G + ((b * 4 + h) * 16 + d) * 16;
    const float rqd = rq[b * 64 + h * 16 + d];
    float L[16], mx = -1e30f;
#pragma unroll
    for (int e = 0; e < 16; ++e) {
      L[e] = g[e] * rqd * rk[b * 64 + h * 16 + e] * tm;
      mx = fmaxf(mx, L[e]);
    }
    float s = 0.f;
#pragma unroll
    for (int e = 0; e < 16; ++e) { L[e] = expf(L[e] - mx); s += L[e]; }
    const float inv = 1.f / s;
#pragma unroll
    for (int e = 0; e < 16; ++e) attn[b][h][d][e] = L[e] * inv;
  }
  __syncthreads();
  for (int s0 = 0; s0 < 32; ++s0) {
    const int idx = t * 32 + s0;
    const int b = idx >> 12, o = (idx >> 6) & 63, c = idx & 63;
    const int h = c >> 4, e = c & 15;
    float a = 0.f;
#pragma unroll
    for (int d = 0; d < 16; ++d) a = fmaf(wpo[o * 64 + h * 16 + d], attn[b][h][d][e], a);
    M1[b][o][c] = a;
  }
  __syncthreads();
  for (int s0 = 0; s0 < 32; ++s0) {
    const int idx = t * 32 + s0;
    const int b = idx >> 12, o = (idx >> 6) & 63, c = idx & 63;
    const int h = c >> 4, e = c & 15;
    float a = 0.f;
    for (int j = 0; j < 64; ++j) a = fmaf(wkv[(64 + o) * 64 + j], M1[b][j][c], a);
    P[(b * 64 + o) * 64 + c] = a;
    float a2 = 0.f;
#pragma unroll
    for (int d = 0; d < 16; ++d) a2 = fmaf(wpof[o * 64 + h * 16 + d], attn[b][h][d][e], a2);
    M2[(b * 64 + o) * 64 + c] = a2;
  }
}

// ---------------- G2: VFP[n][64] = P_b * v   (v = qkv cols 128..191)
__global__ __launch_bounds__(256, 2) void g_pv(
    const u16* __restrict__ qkv, const float* __restrict__ P,
    u16* __restrict__ vfp)
{
  const int l = threadIdx.x & 63, fr = l & 15, fq = l >> 4;
  const int wv = blockIdx.x * 4 + (threadIdx.x >> 6);
  const int nw = gridDim.x * 4;
  const int b = blockIdx.z;
  const float* Pb = P + b * 4096;
  short8 A[4][2];
#pragma unroll
  for (int t = 0; t < 4; ++t)
#pragma unroll
    for (int kh = 0; kh < 2; ++kh)
      A[t][kh] = afrag(Pb, 64, t * 16 + fr, kh * 32 + fq * 8, 64);
  for (int tile = wv; tile < 4096; tile += nw) {
    const size_t n0 = (size_t)b * NPB + (size_t)tile * 16;
    const u16* yb = qkv + (n0 + fr) * 192 + 128 + fq * 8;
    const short8 b0 = *reinterpret_cast<const short8*>(yb);
    const short8 b1 = *reinterpret_cast<const short8*>(yb + 32);
    f32x4 c[4];
#pragma unroll
    for (int t = 0; t < 4; ++t) c[t] = f32x4{0.f, 0.f, 0.f, 0.f};
#pragma unroll
    for (int t = 0; t < 4; ++t) c[t] = mm(A[t][0], b0, c[t]);
#pragma unroll
    for (int t = 0; t < 4; ++t) c[t] = mm(A[t][1], b1, c[t]);
    u16* ob = vfp + (n0 + fr) * 64 + fq * 4;
#pragma unroll
    for (int t = 0; t < 4; ++t) st4(ob + t * 16, c[t]);
  }
}

// ---------------- G3 fused: X2 = x + M2_b*vf (bf16 out) ; Y2 = LN2(X2)
__global__ __launch_bounds__(256, 2) void g_x2ln(
    const u16* __restrict__ vf, const float* __restrict__ M2,
    const float* __restrict__ x, const float* __restrict__ n2w,
    const float* __restrict__ n2b, u16* __restrict__ X2,
    u16* __restrict__ Y2)
{
  const int l = threadIdx.x & 63, fr = l & 15, fq = l >> 4;
  const int wv = blockIdx.x * 4 + (threadIdx.x >> 6);
  const int nw = gridDim.x * 4;
  const int b = blockIdx.z;
  const float* Mb = M2 + b * 4096;
  short8 A[4][2];
#pragma unroll
  for (int t = 0; t < 4; ++t)
#pragma unroll
    for (int kh = 0; kh < 2; ++kh)
      A[t][kh] = afrag(Mb, 64, t * 16 + fr, kh * 32 + fq * 8, 64);
  for (int tile = wv; tile < 4096; tile += nw) {
    const int pix0 = tile * 16;
    const size_t n0 = (size_t)b * NPB + pix0;
    const u16* yb = vf + (n0 + fr) * 64 + fq * 8;
    const short8 b0 = *reinterpret_cast<const short8*>(yb);
    const short8 b1 = *reinterpret_cast<const short8*>(yb + 32);
    f32x4 c[4];
#pragma unroll
    for (int t = 0; t < 4; ++t) c[t] = f32x4{0.f, 0.f, 0.f, 0.f};
#pragma unroll
    for (int t = 0; t < 4; ++t) c[t] = mm(A[t][0], b0, c[t]);
#pragma unroll
    for (int t = 0; t < 4; ++t) c[t] = mm(A[t][1], b1, c[t]);
    const int pix = pix0 + fr;
#pragma unroll
    for (int t = 0; t < 4; ++t)
#pragma unroll
      for (int r = 0; r < 4; ++r)
        c[t][r] += x[((size_t)(b * 64 + t * 16 + fq * 4 + r)) * NPB + pix];
    u16* xb = X2 + (n0 + fr) * 64 + fq * 4;
#pragma unroll
    for (int t = 0; t < 4; ++t) st4(xb + t * 16, c[t]);
    float s = 0.f;
#pragma unroll
    for (int t = 0; t < 4; ++t)
#pragma unroll
      for (int r = 0; r < 4; ++r) s += c[t][r];
    s += __shfl_xor(s, 16); s += __shfl_xor(s, 32);
    const float mu = s * (1.f / 64.f);
    float ss = 0.f;
#pragma unroll
    for (int t = 0; t < 4; ++t)
#pragma unroll
      for (int r = 0; r < 4; ++r) { float d = c[t][r] - mu; ss = fmaf(d, d, ss); }
    ss += __shfl_xor(ss, 16); ss += __shfl_xor(ss, 32);
    const float rstd = rsqrtf(ss * (1.f / 64.f) + 1e-5f);
#pragma unroll
    for (int t = 0; t < 4; ++t)
#pragma unroll
      for (int r = 0; r < 4; ++r) {
        const int oc = t * 16 + fq * 4 + r;
        c[t][r] = (c[t][r] - mu) * rstd * n2w[oc] + n2b[oc];
      }
    u16* ob = Y2 + (n0 + fr) * 64 + fq * 4;
#pragma unroll
    for (int t = 0; t < 4; ++t) st4(ob + t * 16, c[t]);
  }
}

// ---------------- G4: Hpre[n][352] = Win(340x64 padded) * Y2
__global__ __launch_bounds__(256, 2) void g_win(
    const u16* __restrict__ Y2, const float* __restrict__ win,
    u16* __restrict__ hpre)
{
  const int l = threadIdx.x & 63, fr = l & 15, fq = l >> 4;
  const int wv = blockIdx.x * 4 + (threadIdx.x >> 6);
  const int nw = gridDim.x * 4;
  const int half = wv & 1;
  short8 A[11][2];
#pragma unroll
  for (int t = 0; t < 11; ++t)
#pragma unroll
    for (int kh = 0; kh < 2; ++kh) {
      const int col = half * 176 + t * 16 + fr;
      const int row = col < 170 ? col : (col < 176 ? -1 : (col < 346 ? col - 6 : -1));
      A[t][kh] = afrag(win, 64, row, kh * 32 + fq * 8, 64);
    }
  for (int tile = wv >> 1; tile < 8192; tile += (nw >> 1)) {
    const size_t n0 = (size_t)tile * 16;
    const u16* yb = Y2 + (n0 + fr) * 64 + fq * 8;
    const short8 b0 = *reinterpret_cast<const short8*>(yb);
    const short8 b1 = *reinterpret_cast<const short8*>(yb + 32);
    f32x4 c[11];
#pragma unroll
    for (int t = 0; t < 11; ++t) c[t] = f32x4{0.f, 0.f, 0.f, 0.f};
#pragma unroll
    for (int t = 0; t < 11; ++t) c[t] = mm(A[t][0], b0, c[t]);
#pragma unroll
    for (int t = 0; t < 11; ++t) c[t] = mm(A[t][1], b1, c[t]);
    u16* ob = hpre + (n0 + fr) * 352 + half * 176 + fq * 4;
#pragma unroll
    for (int t = 0; t < 11; ++t) st4(ob + t * 16, c[t]);
  }
}

// ---------------- dw3x3 on Hpre + gelu(x1)*x2 fused -> Hg[n][176]
__global__ __launch_bounds__(256, 2) void k_dwg(
    const u16* __restrict__ hpre, u16* __restrict__ hg,
    const float* __restrict__ wdw)
{
  const int gid = blockIdx.x * 256 + threadIdx.x;
  const int cg = gid % 22;
  const int rest = gid / 22;
  const int strip = rest & 32767;
  const int b = rest >> 15;
  const int x0 = strip & 255;
  const int y0 = (strip >> 8) * 2;
  const u16* pin = hpre + (size_t)b * NPB * 352;
  u16* pout = hg + (size_t)b * NPB * 176;
  float acc[2][2][8];
#pragma unroll
  for (int ph = 0; ph < 2; ++ph) {
    float w[9][8];
#pragma unroll
    for (int i = 0; i < 8; ++i) {
      const int c = cg * 8 + i;
      const int row = ph == 0 ? c : 170 + c;
      const bool valid = c < 170;
#pragma unroll
      for (int k = 0; k < 9; ++k) w[k][i] = valid ? wdw[(size_t)row * 9 + k] : 0.f;
    }
    const int colofs = ph == 0 ? cg * 8 : 176 + cg * 8;
#pragma unroll
    for (int oy = 0; oy < 2; ++oy) {
      const int y = y0 + oy;
#pragma unroll
      for (int i = 0; i < 8; ++i) acc[ph][oy][i] = 0.f;
#pragma unroll
      for (int ky = 0; ky < 3; ++ky) {
        const int yy = y + ky - 1;
        if ((unsigned)yy >= 256u) continue;
#pragma unroll
        for (int kx = 0; kx < 3; ++kx) {
          const int xx = x0 + kx - 1;
          if ((unsigned)xx >= 256u) continue;
          const short8 v = *reinterpret_cast<const short8*>(
              pin + ((size_t)(yy * 256 + xx)) * 352 + colofs);
#pragma unroll
          for (int i = 0; i < 8; ++i)
            acc[ph][oy][i] = fmaf(w[ky * 3 + kx][i], bf2f((u16)v[i]), acc[ph][oy][i]);
        }
      }
    }
  }
#pragma unroll
  for (int oy = 0; oy < 2; ++oy) {
    const int y = y0 + oy;
    float g[8];
#pragma unroll
    for (int i = 0; i < 8; ++i) {
      const float a = acc[0][oy][i];
      g[i] = 0.5f * a * (1.f + erff(a * 0.70710678118f)) * acc[1][oy][i];
    }
    uint4 o;
    o.x = pk2(g[0], g[1]); o.y = pk2(g[2], g[3]);
    o.z = pk2(g[4], g[5]); o.w = pk2(g[6], g[7]);
    *reinterpret_cast<uint4*>(pout + ((size_t)(y * 256 + x0)) * 176 + cg * 8) = o;
  }
}

// ---------------- G5: out = X2 + Wout(64x170) * Hg   (f32 channel-major)
__global__ __launch_bounds__(256, 2) void g_out(
    const u16* __restrict__ hg, const float* __restrict__ wout,
    const u16* __restrict__ X2, float* __restrict__ out)
{
  const int l = threadIdx.x & 63, fr = l & 15, fq = l >> 4;
  const int wv = blockIdx.x * 4 + (threadIdx.x >> 6);
  const int nw = gridDim.x * 4;
  short8 A[4][6];
#pragma unroll
  for (int t = 0; t < 4; ++t)
#pragma unroll
    for (int kh = 0; kh < 6; ++kh)
      A[t][kh] = afrag(wout, 170, t * 16 + fr, kh * 32 + fq * 8, 170);
  for (int tile = wv; tile < 8192; tile += nw) {
    const size_t n0 = (size_t)tile * 16;
    f32x4 c[4];
#pragma unroll
    for (int t = 0; t < 4; ++t) c[t] = f32x4{0.f, 0.f, 0.f, 0.f};
#pragma unroll
    for (int kh = 0; kh < 6; ++kh) {
      const short8 bb = *reinterpret_cast<const short8*>(
          hg + (n0 + fr) * 176 + kh * 32 + fq * 8);
#pragma unroll
      for (int t = 0; t < 4; ++t) c[t] = mm(A[t][kh], bb, c[t]);
    }
    const int b = (int)(n0 >> 16);
    const int pix = ((int)n0 & 65535) + fr;
#pragma unroll
    for (int t = 0; t < 4; ++t) {
      const uint2 xv = *reinterpret_cast<const uint2*>(
          X2 + (n0 + fr) * 64 + t * 16 + fq * 4);
      const u16 h0 = (u16)(xv.x & 0xffff), h1 = (u16)(xv.x >> 16);
      const u16 h2 = (u16)(xv.y & 0xffff), h3 = (u16)(xv.y >> 16);
      const int ocb = b * 64 + t * 16 + fq * 4;
      out[((size_t)(ocb + 0)) * NPB + pix] = c[t][0] + bf2f(h0);
      out[((size_t)(ocb + 1)) * NPB + pix] = c[t][1] + bf2f(h1);
      out[((size_t)(ocb + 2)) * NPB + pix] = c[t][2] + bf2f(h2);
      out[((size_t)(ocb + 3)) * NPB + pix] = c[t][3] + bf2f(h3);
    }
  }
}

extern "C" void kernel_launch(void* const* d_in, const int* in_sizes, int n_in,
                              void* d_out, int out_size, void* d_ws, size_t ws_size,
                              hipStream_t stream)
{
  const float* x     = (const float*)d_in[0];
  const float* n1w   = (const float*)d_in[1];
  const float* n1b   = (const float*)d_in[2];
  const float* temp  = (const float*)d_in[3];
  const float* wqkv  = (const float*)d_in[4];
  const float* wqkvd = (const float*)d_in[5];
  const float* wpo   = (const float*)d_in[6];
  const float* wkv   = (const float*)d_in[7];
  const float* wkvd  = (const float*)d_in[8];
  const float* wpof  = (const float*)d_in[9];
  const float* n2w   = (const float*)d_in[10];
  const float* n2b   = (const float*)d_in[11];
  const float* win   = (const float*)d_in[12];
  const float* wdw   = (const float*)d_in[13];
  const float* wout  = (const float*)d_in[14];
  float* out = (float*)d_out;

  char* ws = (char*)d_ws;
  const size_t offA  = 0;                       // 16.78 MB: Y1 / VFP / Y2
  const size_t offB  = 16777216;                // 50.33 MB: QKVp / VF / Hpre(start)
  const size_t offC  = offB + 50331648;         // 50.33 MB: QKV / Hpre(cont)
  const size_t offHg = offC + 50331648;         // 46.14 MB + slack
  const size_t offX2 = offHg + 46137344 + 256;  // 16.78 MB
  const size_t offSm = offX2 + 16777216;

  u16* Y1   = (u16*)(ws + offA);
  u16* VFP  = (u16*)(ws + offA);
  u16* Y2   = (u16*)(ws + offA);
  u16* QKVp = (u16*)(ws + offB);
  u16* VF   = (u16*)(ws + offB);
  u16* Hpre = (u16*)(ws + offB);   // spans B+C (92.3 MB <= 100.7 MB)
  u16* QKV  = (u16*)(ws + offC);
  u16* Hg   = (u16*)(ws + offHg);
  u16* X2   = (u16*)(ws + offX2);
  float* part = (float*)(ws + offSm);                     // 1,179,648 B
  float* G    = (float*)(ws + offSm + 1179648);           // 8 KB
  float* Sq   = (float*)(ws + offSm + 1179648 + 8192);    // 512 B
  float* Sk   = (float*)(ws + offSm + 1179648 + 8704);    // 512 B
  float* P    = (float*)(ws + offSm + 1179648 + 9216);    // 32 KB
  float* M2   = (float*)(ws + offSm + 1179648 + 41984);   // 32 KB

  k_ln1<<<dim3(NPB / 256, BATCH), 256, 0, stream>>>(x, n1w, n1b, Y1);
  g_qkvp<<<dim3(512), 256, 0, stream>>>(Y1, wqkv, QKVp);
  k_dw3p<192, 0><<<dim3(3072), 256, 0, stream>>>(QKVp, QKV, wqkvd);
  k_gram_p<<<dim3(128, 4, BATCH), 256, 0, stream>>>(QKV, part);
  k_gram_red<<<dim3(BATCH * 4), 320, 0, stream>>>(part, G, Sq, Sk);
  k_attn<<<dim3(1), 256, 0, stream>>>(G, Sq, Sk, temp, wpo, wkv, wpof, P, M2);
  g_pv<<<dim3(256, 1, BATCH), 256, 0, stream>>>(QKV, P, VFP);
  k_dw3p<64, 64><<<dim3(1024), 256, 0, stream>>>(VFP, VF, wkvd);
  g_x2ln<<<dim3(256, 1, BATCH), 256, 0, stream>>>(VF, M2, x, n2w, n2b, X2, Y2);
  g_win<<<dim3(512), 256, 0, stream>>>(Y2, win, Hpre);
  k_dwg<<<dim3(5632), 256, 0, stream>>>(Hpre, Hg, wdw);
  g_out<<<dim3(512), 256, 0, stream>>>(Hg, wout, X2, out);
}